// Round 1
// baseline (4285.539 us; speedup 1.0000x reference)
//
#include <hip/hip_runtime.h>
#include <hip/hip_bf16.h>
#include <cstdint>

#define T_DIM 4096
#define D_DIM 4096
#define I_DIM 12288
#define GRP   128

typedef __attribute__((ext_vector_type(8))) short bf16x8;   // MFMA A/B frag (8 bf16)
typedef __attribute__((ext_vector_type(4))) float f32x4;    // MFMA C/D frag
typedef __attribute__((ext_vector_type(4))) int   int32x4;

typedef __attribute__((address_space(3))) void lds_void;
typedef const __attribute__((address_space(1))) void gmem_void;

// f32 -> bf16 bits, round-to-nearest-even (finite inputs)
static __device__ __forceinline__ unsigned short f2bf(float f) {
    unsigned int u = __float_as_uint(f);
    u += 0x7FFFu + ((u >> 16) & 1u);
    return (unsigned short)(u >> 16);
}
static __device__ __forceinline__ float bf2f(unsigned short b) {
    return __uint_as_float(((unsigned int)b) << 16);
}

// ---------------- Hadamard (blockwise-128 FWHT), one wave per group, 2 elems/lane ----
// element e = 2*lane + i ; stage stride 1 in-lane, strides 2..64 via shfl_xor(lane^m)
__global__ void had_f32_to_bf16(const float* __restrict__ in, unsigned short* __restrict__ out,
                                int ngroups) {
    int gid = blockIdx.x * (blockDim.x >> 6) + (threadIdx.x >> 6);
    if (gid >= ngroups) return;
    int lane = threadIdx.x & 63;
    const float2 v2 = *reinterpret_cast<const float2*>(in + (size_t)gid * 128 + lane * 2);
    float v0 = v2.x, v1 = v2.y;
    { float t0 = v0 + v1, t1 = v0 - v1; v0 = t0; v1 = t1; }   // stride 1
#pragma unroll
    for (int m = 1; m <= 32; m <<= 1) {                        // strides 2..64
        float b0 = __shfl_xor(v0, m);
        float b1 = __shfl_xor(v1, m);
        if (lane & m) { v0 = b0 - v0; v1 = b1 - v1; }
        else          { v0 = v0 + b0; v1 = v1 + b1; }
    }
    const float s = 0.08838834764831843f;  // 1/sqrt(128)
    unsigned int o = (unsigned int)f2bf(v0 * s) | ((unsigned int)f2bf(v1 * s) << 16);
    *reinterpret_cast<unsigned int*>(out + (size_t)gid * 128 + lane * 2) = o;
}

__global__ void had_bf16_inplace(unsigned short* __restrict__ buf, int ngroups) {
    int gid = blockIdx.x * (blockDim.x >> 6) + (threadIdx.x >> 6);
    if (gid >= ngroups) return;
    int lane = threadIdx.x & 63;
    unsigned int pv = *reinterpret_cast<const unsigned int*>(buf + (size_t)gid * 128 + lane * 2);
    float v0 = __uint_as_float((pv & 0xFFFFu) << 16);
    float v1 = __uint_as_float(pv & 0xFFFF0000u);
    { float t0 = v0 + v1, t1 = v0 - v1; v0 = t0; v1 = t1; }
#pragma unroll
    for (int m = 1; m <= 32; m <<= 1) {
        float b0 = __shfl_xor(v0, m);
        float b1 = __shfl_xor(v1, m);
        if (lane & m) { v0 = b0 - v0; v1 = b1 - v1; }
        else          { v0 = v0 + b0; v1 = v1 + b1; }
    }
    const float s = 0.08838834764831843f;
    unsigned int o = (unsigned int)f2bf(v0 * s) | ((unsigned int)f2bf(v1 * s) << 16);
    *reinterpret_cast<unsigned int*>(buf + (size_t)gid * 128 + lane * 2) = o;
}

// ---------------- fused gate/up GEMM: h = silu(Xr Wg^T) * (Xr Wu^T), bf16 out -------
// 128x128 tile, BK=64, 4 waves each owning a 64x64 quadrant (4x4 frags of 16x16x32)
__global__ __launch_bounds__(256, 2)
void gemm_gateup(const unsigned short* __restrict__ Xr,                 // [T,D] bf16
                 const int* __restrict__ Wg, const float* __restrict__ Sg,
                 const int* __restrict__ Wu, const float* __restrict__ Su,
                 unsigned short* __restrict__ H)                        // [T,I] bf16
{
    __shared__ __align__(16) unsigned short lA [128 * 64];
    __shared__ __align__(16) unsigned short lBg[128 * 64];
    __shared__ __align__(16) unsigned short lBu[128 * 64];

    const int MT = T_DIM / 128;                 // 32
    const int bid = blockIdx.x;
    const int m0 = (bid % MT) * 128;            // consecutive blocks share the B panel
    const int n0 = (bid / MT) * 128;

    const int tid  = threadIdx.x;
    const int lane = tid & 63;
    const int wid  = tid >> 6;
    const int wr = wid >> 1, wc = wid & 1;

    f32x4 accG[4][4], accU[4][4];
#pragma unroll
    for (int i = 0; i < 4; ++i)
#pragma unroll
        for (int j = 0; j < 4; ++j) { accG[i][j] = (f32x4)0.0f; accU[i][j] = (f32x4)0.0f; }

    const int arow = lane >> 3;                 // A stage: lane covers row chunk*8+arow
    const int acol = (lane & 7) * 8;            //          cols acol..acol+7
    const int SStride = D_DIM / GRP;            // 32

    for (int k0 = 0; k0 < D_DIM; k0 += 64) {
        __syncthreads();                        // previous compute done before overwrite
        // ---- A: global -> LDS direct, 16B/lane, 4 wave-issues per wave ----
#pragma unroll
        for (int it = 0; it < 4; ++it) {
            int chunk = wid * 4 + it;
            const unsigned short* gp =
                Xr + (size_t)(m0 + chunk * 8 + arow) * D_DIM + k0 + acol;
            __builtin_amdgcn_global_load_lds((gmem_void*)gp,
                                             (lds_void*)(lA + chunk * 512), 16, 0, 0);
        }
        // ---- B: int4-in-int32 -> dequant -> bf16 LDS ([n][k], k-contig) ----
        const int g = k0 >> 7;
#pragma unroll
        for (int i = 0; i < 8; ++i) {
            int linear = i * 1024 + tid * 4;
            int r = linear >> 6;
            int c = linear & 63;
            const int32x4 wg = *reinterpret_cast<const int32x4*>(Wg + (size_t)(n0 + r) * D_DIM + k0 + c);
            const int32x4 wu = *reinterpret_cast<const int32x4*>(Wu + (size_t)(n0 + r) * D_DIM + k0 + c);
            float scg = Sg[(size_t)(n0 + r) * SStride + g];
            float scu = Su[(size_t)(n0 + r) * SStride + g];
            unsigned int g01 = (unsigned int)f2bf((float)(wg.x - 8) * scg) |
                               ((unsigned int)f2bf((float)(wg.y - 8) * scg) << 16);
            unsigned int g23 = (unsigned int)f2bf((float)(wg.z - 8) * scg) |
                               ((unsigned int)f2bf((float)(wg.w - 8) * scg) << 16);
            unsigned int u01 = (unsigned int)f2bf((float)(wu.x - 8) * scu) |
                               ((unsigned int)f2bf((float)(wu.y - 8) * scu) << 16);
            unsigned int u23 = (unsigned int)f2bf((float)(wu.z - 8) * scu) |
                               ((unsigned int)f2bf((float)(wu.w - 8) * scu) << 16);
            *reinterpret_cast<uint2*>(lBg + r * 64 + c) = make_uint2(g01, g23);
            *reinterpret_cast<uint2*>(lBu + r * 64 + c) = make_uint2(u01, u23);
        }
        __syncthreads();                        // implicit vmcnt(0) drains global_load_lds
        // ---- compute: 2 k-substeps x (4 A-frags, 4+4 B-frags, 16+16 MFMA) ----
#pragma unroll
        for (int ks = 0; ks < 2; ++ks) {
            const int koff = ks * 32 + (lane >> 4) * 8;
            bf16x8 af[4], bg[4], bu[4];
#pragma unroll
            for (int mi = 0; mi < 4; ++mi)
                af[mi] = *reinterpret_cast<const bf16x8*>(lA + (wr * 64 + mi * 16 + (lane & 15)) * 64 + koff);
#pragma unroll
            for (int ni = 0; ni < 4; ++ni) {
                bg[ni] = *reinterpret_cast<const bf16x8*>(lBg + (wc * 64 + ni * 16 + (lane & 15)) * 64 + koff);
                bu[ni] = *reinterpret_cast<const bf16x8*>(lBu + (wc * 64 + ni * 16 + (lane & 15)) * 64 + koff);
            }
#pragma unroll
            for (int mi = 0; mi < 4; ++mi)
#pragma unroll
                for (int ni = 0; ni < 4; ++ni) {
                    accG[mi][ni] = __builtin_amdgcn_mfma_f32_16x16x32_bf16(af[mi], bg[ni], accG[mi][ni], 0, 0, 0);
                    accU[mi][ni] = __builtin_amdgcn_mfma_f32_16x16x32_bf16(af[mi], bu[ni], accU[mi][ni], 0, 0, 0);
                }
        }
    }

    // ---- epilogue: silu(gate)*up -> bf16 H.  D-frag: col=lane&15, row=(lane>>4)*4+r
#pragma unroll
    for (int mi = 0; mi < 4; ++mi)
#pragma unroll
        for (int ni = 0; ni < 4; ++ni) {
            const int col = n0 + wc * 64 + ni * 16 + (lane & 15);
#pragma unroll
            for (int r = 0; r < 4; ++r) {
                const int row = m0 + wr * 64 + mi * 16 + (lane >> 4) * 4 + r;
                float gv = accG[mi][ni][r];
                float uv = accU[mi][ni][r];
                float hv = (gv / (1.0f + __expf(-gv))) * uv;
                H[(size_t)row * I_DIM + col] = f2bf(hv);
            }
        }
}

// ---------------- down GEMM: out = Hr Wd^T, f32 out ---------------------------------
__global__ __launch_bounds__(256, 2)
void gemm_down(const unsigned short* __restrict__ Hr,                   // [T,I] bf16
               const int* __restrict__ Wd, const float* __restrict__ Sd,
               float* __restrict__ Out)                                 // [T,D] f32
{
    __shared__ __align__(16) unsigned short lA[128 * 64];
    __shared__ __align__(16) unsigned short lB[128 * 64];

    const int MT = T_DIM / 128;                 // 32
    const int bid = blockIdx.x;
    const int m0 = (bid % MT) * 128;
    const int n0 = (bid / MT) * 128;

    const int tid  = threadIdx.x;
    const int lane = tid & 63;
    const int wid  = tid >> 6;
    const int wr = wid >> 1, wc = wid & 1;

    f32x4 acc[4][4];
#pragma unroll
    for (int i = 0; i < 4; ++i)
#pragma unroll
        for (int j = 0; j < 4; ++j) acc[i][j] = (f32x4)0.0f;

    const int arow = lane >> 3;
    const int acol = (lane & 7) * 8;
    const int SStride = I_DIM / GRP;            // 96

    for (int k0 = 0; k0 < I_DIM; k0 += 64) {
        __syncthreads();
#pragma unroll
        for (int it = 0; it < 4; ++it) {
            int chunk = wid * 4 + it;
            const unsigned short* gp =
                Hr + (size_t)(m0 + chunk * 8 + arow) * I_DIM + k0 + acol;
            __builtin_amdgcn_global_load_lds((gmem_void*)gp,
                                             (lds_void*)(lA + chunk * 512), 16, 0, 0);
        }
        const int g = k0 >> 7;
#pragma unroll
        for (int i = 0; i < 8; ++i) {
            int linear = i * 1024 + tid * 4;
            int r = linear >> 6;
            int c = linear & 63;
            const int32x4 wd = *reinterpret_cast<const int32x4*>(Wd + (size_t)(n0 + r) * I_DIM + k0 + c);
            float sc = Sd[(size_t)(n0 + r) * SStride + g];
            unsigned int d01 = (unsigned int)f2bf((float)(wd.x - 8) * sc) |
                               ((unsigned int)f2bf((float)(wd.y - 8) * sc) << 16);
            unsigned int d23 = (unsigned int)f2bf((float)(wd.z - 8) * sc) |
                               ((unsigned int)f2bf((float)(wd.w - 8) * sc) << 16);
            *reinterpret_cast<uint2*>(lB + r * 64 + c) = make_uint2(d01, d23);
        }
        __syncthreads();
#pragma unroll
        for (int ks = 0; ks < 2; ++ks) {
            const int koff = ks * 32 + (lane >> 4) * 8;
            bf16x8 af[4], bf[4];
#pragma unroll
            for (int mi = 0; mi < 4; ++mi)
                af[mi] = *reinterpret_cast<const bf16x8*>(lA + (wr * 64 + mi * 16 + (lane & 15)) * 64 + koff);
#pragma unroll
            for (int ni = 0; ni < 4; ++ni)
                bf[ni] = *reinterpret_cast<const bf16x8*>(lB + (wc * 64 + ni * 16 + (lane & 15)) * 64 + koff);
#pragma unroll
            for (int mi = 0; mi < 4; ++mi)
#pragma unroll
                for (int ni = 0; ni < 4; ++ni)
                    acc[mi][ni] = __builtin_amdgcn_mfma_f32_16x16x32_bf16(af[mi], bf[ni], acc[mi][ni], 0, 0, 0);
        }
    }

#pragma unroll
    for (int mi = 0; mi < 4; ++mi)
#pragma unroll
        for (int ni = 0; ni < 4; ++ni) {
            const int col = n0 + wc * 64 + ni * 16 + (lane & 15);
#pragma unroll
            for (int r = 0; r < 4; ++r) {
                const int row = m0 + wr * 64 + mi * 16 + (lane >> 4) * 4 + r;
                Out[(size_t)row * D_DIM + col] = acc[mi][ni][r];
            }
        }
}

extern "C" void kernel_launch(void* const* d_in, const int* in_sizes, int n_in,
                              void* d_out, int out_size, void* d_ws, size_t ws_size,
                              hipStream_t stream) {
    const float* x       = (const float*)d_in[0];
    const int*   wq_gate = (const int*)d_in[1];
    const float* s_gate  = (const float*)d_in[2];
    const int*   wq_up   = (const int*)d_in[3];
    const float* s_up    = (const float*)d_in[4];
    const int*   wq_down = (const int*)d_in[5];
    const float* s_down  = (const float*)d_in[6];
    float* out = (float*)d_out;

    // workspace: xr [T,D] bf16 (33.5 MB) | h [T,I] bf16 (100.7 MB)  => 134.2 MB
    unsigned short* xr = (unsigned short*)d_ws;
    unsigned short* h  = xr + (size_t)T_DIM * D_DIM;

    // 1) xr = hadamard(x), cast bf16
    {
        int ngroups = T_DIM * D_DIM / 128;          // 131072, 4 groups/block
        had_f32_to_bf16<<<dim3(ngroups / 4), dim3(256), 0, stream>>>(x, xr, ngroups);
    }
    // 2) h = silu(xr Wg^T) * (xr Wu^T)
    gemm_gateup<<<dim3((T_DIM / 128) * (I_DIM / 128)), dim3(256), 0, stream>>>(
        xr, wq_gate, s_gate, wq_up, s_up, h);
    // 3) h = hadamard(h) in-place (each wave owns its 128-group)
    {
        int ngroups = T_DIM * I_DIM / 128;          // 393216
        had_bf16_inplace<<<dim3(ngroups / 4), dim3(256), 0, stream>>>(h, ngroups);
    }
    // 4) out = h Wd^T (f32)
    gemm_down<<<dim3((T_DIM / 128) * (D_DIM / 128)), dim3(256), 0, stream>>>(
        h, wq_down, s_down, out);
}

// Round 2
// 1727.762 us; speedup vs baseline: 2.4804x; 2.4804x over previous
//
#include <hip/hip_runtime.h>
#include <hip/hip_bf16.h>
#include <cstdint>

#define T_DIM 4096
#define D_DIM 4096
#define I_DIM 12288
#define GRP   128

typedef __attribute__((ext_vector_type(8))) short bf16x8;   // MFMA A/B frag (8 bf16)
typedef __attribute__((ext_vector_type(4))) float f32x4;    // MFMA C/D frag
typedef __attribute__((ext_vector_type(4))) int   int32x4;

typedef __attribute__((address_space(3))) void lds_void;
typedef const __attribute__((address_space(1))) void gmem_void;

// f32 -> bf16 bits, round-to-nearest-even (finite inputs)
static __device__ __forceinline__ unsigned short f2bf(float f) {
    unsigned int u = __float_as_uint(f);
    u += 0x7FFFu + ((u >> 16) & 1u);
    return (unsigned short)(u >> 16);
}

// ---------------- Hadamard (blockwise-128 FWHT), one wave per group, 2 elems/lane ----
__global__ void had_f32_to_bf16(const float* __restrict__ in, unsigned short* __restrict__ out,
                                int ngroups) {
    int gid = blockIdx.x * (blockDim.x >> 6) + (threadIdx.x >> 6);
    if (gid >= ngroups) return;
    int lane = threadIdx.x & 63;
    const float2 v2 = *reinterpret_cast<const float2*>(in + (size_t)gid * 128 + lane * 2);
    float v0 = v2.x, v1 = v2.y;
    { float t0 = v0 + v1, t1 = v0 - v1; v0 = t0; v1 = t1; }
#pragma unroll
    for (int m = 1; m <= 32; m <<= 1) {
        float b0 = __shfl_xor(v0, m);
        float b1 = __shfl_xor(v1, m);
        if (lane & m) { v0 = b0 - v0; v1 = b1 - v1; }
        else          { v0 = v0 + b0; v1 = v1 + b1; }
    }
    const float s = 0.08838834764831843f;  // 1/sqrt(128)
    unsigned int o = (unsigned int)f2bf(v0 * s) | ((unsigned int)f2bf(v1 * s) << 16);
    *reinterpret_cast<unsigned int*>(out + (size_t)gid * 128 + lane * 2) = o;
}

__global__ void had_bf16_inplace(unsigned short* __restrict__ buf, int ngroups) {
    int gid = blockIdx.x * (blockDim.x >> 6) + (threadIdx.x >> 6);
    if (gid >= ngroups) return;
    int lane = threadIdx.x & 63;
    unsigned int pv = *reinterpret_cast<const unsigned int*>(buf + (size_t)gid * 128 + lane * 2);
    float v0 = __uint_as_float((pv & 0xFFFFu) << 16);
    float v1 = __uint_as_float(pv & 0xFFFF0000u);
    { float t0 = v0 + v1, t1 = v0 - v1; v0 = t0; v1 = t1; }
#pragma unroll
    for (int m = 1; m <= 32; m <<= 1) {
        float b0 = __shfl_xor(v0, m);
        float b1 = __shfl_xor(v1, m);
        if (lane & m) { v0 = b0 - v0; v1 = b1 - v1; }
        else          { v0 = v0 + b0; v1 = v1 + b1; }
    }
    const float s = 0.08838834764831843f;
    unsigned int o = (unsigned int)f2bf(v0 * s) | ((unsigned int)f2bf(v1 * s) << 16);
    *reinterpret_cast<unsigned int*>(buf + (size_t)gid * 128 + lane * 2) = o;
}

// ---------------- weight dequant: int4-in-int32 [O,In] -> bf16 [O,In] ----------------
// one thread per 8 elements; memory-bound (32B in + 16B out per thread)
__global__ void dequant_w(const int* __restrict__ Wq, const float* __restrict__ S,
                          unsigned short* __restrict__ Wbf, int In, int total8) {
    int t = blockIdx.x * blockDim.x + threadIdx.x;
    if (t >= total8) return;
    size_t base = (size_t)t * 8;
    int col = (int)(base & (size_t)(In - 1) | 0);   // In is 4096 or 12288 (not pow2!) - compute generally
    // In may be 12288 (not a power of two): use div/mod via 64-bit
    size_t row = base / (size_t)In;
    col = (int)(base - row * (size_t)In);
    float sc = S[row * (size_t)(In >> 7) + (col >> 7)];
    const int32x4* p = reinterpret_cast<const int32x4*>(Wq + base);
    int32x4 a = p[0], b = p[1];
    float nsc = -8.0f * sc;
    unsigned int o0 = (unsigned int)f2bf((float)a.x * sc + nsc) |
                      ((unsigned int)f2bf((float)a.y * sc + nsc) << 16);
    unsigned int o1 = (unsigned int)f2bf((float)a.z * sc + nsc) |
                      ((unsigned int)f2bf((float)a.w * sc + nsc) << 16);
    unsigned int o2 = (unsigned int)f2bf((float)b.x * sc + nsc) |
                      ((unsigned int)f2bf((float)b.y * sc + nsc) << 16);
    unsigned int o3 = (unsigned int)f2bf((float)b.z * sc + nsc) |
                      ((unsigned int)f2bf((float)b.w * sc + nsc) << 16);
    *reinterpret_cast<uint4*>(Wbf + base) = make_uint4(o0, o1, o2, o3);
}

// ---------------- fused gate/up GEMM (pure bf16): h = silu(Xr Wg^T) * (Xr Wu^T) -----
// m97 structure: 128x128 tile, BK=64, 4 waves, A+B staged via global_load_lds w=16
__global__ __launch_bounds__(256, 2)
void gemm_gateup_bf(const unsigned short* __restrict__ Xr,              // [T,D] bf16
                    const unsigned short* __restrict__ Wg,              // [I,D] bf16
                    const unsigned short* __restrict__ Wu,              // [I,D] bf16
                    unsigned short* __restrict__ H)                     // [T,I] bf16
{
    __shared__ __align__(16) unsigned short lA [128 * 64];
    __shared__ __align__(16) unsigned short lBg[128 * 64];
    __shared__ __align__(16) unsigned short lBu[128 * 64];

    const int MT = T_DIM / 128;                 // 32
    const int bid = blockIdx.x;
    const int m0 = (bid % MT) * 128;            // consecutive blocks share the B panel
    const int n0 = (bid / MT) * 128;

    const int tid  = threadIdx.x;
    const int lane = tid & 63;
    const int wid  = tid >> 6;
    const int wr = wid >> 1, wc = wid & 1;

    f32x4 accG[4][4], accU[4][4];
#pragma unroll
    for (int i = 0; i < 4; ++i)
#pragma unroll
        for (int j = 0; j < 4; ++j) { accG[i][j] = (f32x4)0.0f; accU[i][j] = (f32x4)0.0f; }

    const int srow = lane >> 3;                 // stage: 8 rows / wave-issue
    const int scol = (lane & 7) * 8;            // 8 bf16 = 16B per lane

    for (int k0 = 0; k0 < D_DIM; k0 += 64) {
        __syncthreads();                        // previous compute done before overwrite
#pragma unroll
        for (int it = 0; it < 4; ++it) {
            int chunk = wid * 4 + it;           // 16 chunks of 8 rows
            size_t roff = (size_t)(m0 + chunk * 8 + srow) * D_DIM + k0 + scol;
            __builtin_amdgcn_global_load_lds((gmem_void*)(Xr + roff),
                                             (lds_void*)(lA + chunk * 512), 16, 0, 0);
            size_t goff = (size_t)(n0 + chunk * 8 + srow) * D_DIM + k0 + scol;
            __builtin_amdgcn_global_load_lds((gmem_void*)(Wg + goff),
                                             (lds_void*)(lBg + chunk * 512), 16, 0, 0);
            __builtin_amdgcn_global_load_lds((gmem_void*)(Wu + goff),
                                             (lds_void*)(lBu + chunk * 512), 16, 0, 0);
        }
        __syncthreads();                        // drains vmcnt + lgkm
#pragma unroll
        for (int ks = 0; ks < 2; ++ks) {
            const int koff = ks * 32 + (lane >> 4) * 8;
            bf16x8 af[4], bg[4], bu[4];
#pragma unroll
            for (int mi = 0; mi < 4; ++mi)
                af[mi] = *reinterpret_cast<const bf16x8*>(lA + (wr * 64 + mi * 16 + (lane & 15)) * 64 + koff);
#pragma unroll
            for (int ni = 0; ni < 4; ++ni) {
                bg[ni] = *reinterpret_cast<const bf16x8*>(lBg + (wc * 64 + ni * 16 + (lane & 15)) * 64 + koff);
                bu[ni] = *reinterpret_cast<const bf16x8*>(lBu + (wc * 64 + ni * 16 + (lane & 15)) * 64 + koff);
            }
#pragma unroll
            for (int mi = 0; mi < 4; ++mi)
#pragma unroll
                for (int ni = 0; ni < 4; ++ni) {
                    accG[mi][ni] = __builtin_amdgcn_mfma_f32_16x16x32_bf16(af[mi], bg[ni], accG[mi][ni], 0, 0, 0);
                    accU[mi][ni] = __builtin_amdgcn_mfma_f32_16x16x32_bf16(af[mi], bu[ni], accU[mi][ni], 0, 0, 0);
                }
        }
    }

#pragma unroll
    for (int mi = 0; mi < 4; ++mi)
#pragma unroll
        for (int ni = 0; ni < 4; ++ni) {
            const int col = n0 + wc * 64 + ni * 16 + (lane & 15);
#pragma unroll
            for (int r = 0; r < 4; ++r) {
                const int row = m0 + wr * 64 + mi * 16 + (lane >> 4) * 4 + r;
                float gv = accG[mi][ni][r];
                float uv = accU[mi][ni][r];
                float hv = (gv / (1.0f + __expf(-gv))) * uv;
                H[(size_t)row * I_DIM + col] = f2bf(hv);
            }
        }
}

// ---------------- down GEMM (pure bf16): out = Hr Wd^T, f32 out ----------------------
__global__ __launch_bounds__(256, 2)
void gemm_down_bf(const unsigned short* __restrict__ Hr,                // [T,I] bf16
                  const unsigned short* __restrict__ Wd,                // [D,I] bf16
                  float* __restrict__ Out)                              // [T,D] f32
{
    __shared__ __align__(16) unsigned short lA[128 * 64];
    __shared__ __align__(16) unsigned short lB[128 * 64];

    const int MT = T_DIM / 128;                 // 32
    const int bid = blockIdx.x;
    const int m0 = (bid % MT) * 128;
    const int n0 = (bid / MT) * 128;

    const int tid  = threadIdx.x;
    const int lane = tid & 63;
    const int wid  = tid >> 6;
    const int wr = wid >> 1, wc = wid & 1;

    f32x4 acc[4][4];
#pragma unroll
    for (int i = 0; i < 4; ++i)
#pragma unroll
        for (int j = 0; j < 4; ++j) acc[i][j] = (f32x4)0.0f;

    const int srow = lane >> 3;
    const int scol = (lane & 7) * 8;

    for (int k0 = 0; k0 < I_DIM; k0 += 64) {
        __syncthreads();
#pragma unroll
        for (int it = 0; it < 4; ++it) {
            int chunk = wid * 4 + it;
            size_t roff = (size_t)(m0 + chunk * 8 + srow) * I_DIM + k0 + scol;
            __builtin_amdgcn_global_load_lds((gmem_void*)(Hr + roff),
                                             (lds_void*)(lA + chunk * 512), 16, 0, 0);
            size_t goff = (size_t)(n0 + chunk * 8 + srow) * I_DIM + k0 + scol;
            __builtin_amdgcn_global_load_lds((gmem_void*)(Wd + goff),
                                             (lds_void*)(lB + chunk * 512), 16, 0, 0);
        }
        __syncthreads();
#pragma unroll
        for (int ks = 0; ks < 2; ++ks) {
            const int koff = ks * 32 + (lane >> 4) * 8;
            bf16x8 af[4], bfr[4];
#pragma unroll
            for (int mi = 0; mi < 4; ++mi)
                af[mi] = *reinterpret_cast<const bf16x8*>(lA + (wr * 64 + mi * 16 + (lane & 15)) * 64 + koff);
#pragma unroll
            for (int ni = 0; ni < 4; ++ni)
                bfr[ni] = *reinterpret_cast<const bf16x8*>(lB + (wc * 64 + ni * 16 + (lane & 15)) * 64 + koff);
#pragma unroll
            for (int mi = 0; mi < 4; ++mi)
#pragma unroll
                for (int ni = 0; ni < 4; ++ni)
                    acc[mi][ni] = __builtin_amdgcn_mfma_f32_16x16x32_bf16(af[mi], bfr[ni], acc[mi][ni], 0, 0, 0);
        }
    }

#pragma unroll
    for (int mi = 0; mi < 4; ++mi)
#pragma unroll
        for (int ni = 0; ni < 4; ++ni) {
            const int col = n0 + wc * 64 + ni * 16 + (lane & 15);
#pragma unroll
            for (int r = 0; r < 4; ++r) {
                const int row = m0 + wr * 64 + mi * 16 + (lane >> 4) * 4 + r;
                Out[(size_t)row * D_DIM + col] = acc[mi][ni][r];
            }
        }
}

// ================== FALLBACK (round-1 verified): in-loop dequant GEMMs ==============
__global__ __launch_bounds__(256, 2)
void gemm_gateup_fb(const unsigned short* __restrict__ Xr,
                    const int* __restrict__ Wg, const float* __restrict__ Sg,
                    const int* __restrict__ Wu, const float* __restrict__ Su,
                    unsigned short* __restrict__ H)
{
    __shared__ __align__(16) unsigned short lA [128 * 64];
    __shared__ __align__(16) unsigned short lBg[128 * 64];
    __shared__ __align__(16) unsigned short lBu[128 * 64];
    const int MT = T_DIM / 128;
    const int bid = blockIdx.x;
    const int m0 = (bid % MT) * 128;
    const int n0 = (bid / MT) * 128;
    const int tid  = threadIdx.x;
    const int lane = tid & 63;
    const int wid  = tid >> 6;
    const int wr = wid >> 1, wc = wid & 1;
    f32x4 accG[4][4], accU[4][4];
#pragma unroll
    for (int i = 0; i < 4; ++i)
#pragma unroll
        for (int j = 0; j < 4; ++j) { accG[i][j] = (f32x4)0.0f; accU[i][j] = (f32x4)0.0f; }
    const int arow = lane >> 3;
    const int acol = (lane & 7) * 8;
    const int SStride = D_DIM / GRP;
    for (int k0 = 0; k0 < D_DIM; k0 += 64) {
        __syncthreads();
#pragma unroll
        for (int it = 0; it < 4; ++it) {
            int chunk = wid * 4 + it;
            const unsigned short* gp = Xr + (size_t)(m0 + chunk * 8 + arow) * D_DIM + k0 + acol;
            __builtin_amdgcn_global_load_lds((gmem_void*)gp, (lds_void*)(lA + chunk * 512), 16, 0, 0);
        }
        const int g = k0 >> 7;
#pragma unroll
        for (int i = 0; i < 8; ++i) {
            int linear = i * 1024 + tid * 4;
            int r = linear >> 6;
            int c = linear & 63;
            const int32x4 wg = *reinterpret_cast<const int32x4*>(Wg + (size_t)(n0 + r) * D_DIM + k0 + c);
            const int32x4 wu = *reinterpret_cast<const int32x4*>(Wu + (size_t)(n0 + r) * D_DIM + k0 + c);
            float scg = Sg[(size_t)(n0 + r) * SStride + g];
            float scu = Su[(size_t)(n0 + r) * SStride + g];
            unsigned int g01 = (unsigned int)f2bf((float)(wg.x - 8) * scg) | ((unsigned int)f2bf((float)(wg.y - 8) * scg) << 16);
            unsigned int g23 = (unsigned int)f2bf((float)(wg.z - 8) * scg) | ((unsigned int)f2bf((float)(wg.w - 8) * scg) << 16);
            unsigned int u01 = (unsigned int)f2bf((float)(wu.x - 8) * scu) | ((unsigned int)f2bf((float)(wu.y - 8) * scu) << 16);
            unsigned int u23 = (unsigned int)f2bf((float)(wu.z - 8) * scu) | ((unsigned int)f2bf((float)(wu.w - 8) * scu) << 16);
            *reinterpret_cast<uint2*>(lBg + r * 64 + c) = make_uint2(g01, g23);
            *reinterpret_cast<uint2*>(lBu + r * 64 + c) = make_uint2(u01, u23);
        }
        __syncthreads();
#pragma unroll
        for (int ks = 0; ks < 2; ++ks) {
            const int koff = ks * 32 + (lane >> 4) * 8;
            bf16x8 af[4], bg[4], bu[4];
#pragma unroll
            for (int mi = 0; mi < 4; ++mi)
                af[mi] = *reinterpret_cast<const bf16x8*>(lA + (wr * 64 + mi * 16 + (lane & 15)) * 64 + koff);
#pragma unroll
            for (int ni = 0; ni < 4; ++ni) {
                bg[ni] = *reinterpret_cast<const bf16x8*>(lBg + (wc * 64 + ni * 16 + (lane & 15)) * 64 + koff);
                bu[ni] = *reinterpret_cast<const bf16x8*>(lBu + (wc * 64 + ni * 16 + (lane & 15)) * 64 + koff);
            }
#pragma unroll
            for (int mi = 0; mi < 4; ++mi)
#pragma unroll
                for (int ni = 0; ni < 4; ++ni) {
                    accG[mi][ni] = __builtin_amdgcn_mfma_f32_16x16x32_bf16(af[mi], bg[ni], accG[mi][ni], 0, 0, 0);
                    accU[mi][ni] = __builtin_amdgcn_mfma_f32_16x16x32_bf16(af[mi], bu[ni], accU[mi][ni], 0, 0, 0);
                }
        }
    }
#pragma unroll
    for (int mi = 0; mi < 4; ++mi)
#pragma unroll
        for (int ni = 0; ni < 4; ++ni) {
            const int col = n0 + wc * 64 + ni * 16 + (lane & 15);
#pragma unroll
            for (int r = 0; r < 4; ++r) {
                const int row = m0 + wr * 64 + mi * 16 + (lane >> 4) * 4 + r;
                float gv = accG[mi][ni][r];
                float uv = accU[mi][ni][r];
                float hv = (gv / (1.0f + __expf(-gv))) * uv;
                H[(size_t)row * I_DIM + col] = f2bf(hv);
            }
        }
}

__global__ __launch_bounds__(256, 2)
void gemm_down_fb(const unsigned short* __restrict__ Hr,
                  const int* __restrict__ Wd, const float* __restrict__ Sd,
                  float* __restrict__ Out)
{
    __shared__ __align__(16) unsigned short lA[128 * 64];
    __shared__ __align__(16) unsigned short lB[128 * 64];
    const int MT = T_DIM / 128;
    const int bid = blockIdx.x;
    const int m0 = (bid % MT) * 128;
    const int n0 = (bid / MT) * 128;
    const int tid  = threadIdx.x;
    const int lane = tid & 63;
    const int wid  = tid >> 6;
    const int wr = wid >> 1, wc = wid & 1;
    f32x4 acc[4][4];
#pragma unroll
    for (int i = 0; i < 4; ++i)
#pragma unroll
        for (int j = 0; j < 4; ++j) acc[i][j] = (f32x4)0.0f;
    const int arow = lane >> 3;
    const int acol = (lane & 7) * 8;
    const int SStride = I_DIM / GRP;
    for (int k0 = 0; k0 < I_DIM; k0 += 64) {
        __syncthreads();
#pragma unroll
        for (int it = 0; it < 4; ++it) {
            int chunk = wid * 4 + it;
            const unsigned short* gp = Hr + (size_t)(m0 + chunk * 8 + arow) * I_DIM + k0 + acol;
            __builtin_amdgcn_global_load_lds((gmem_void*)gp, (lds_void*)(lA + chunk * 512), 16, 0, 0);
        }
        const int g = k0 >> 7;
#pragma unroll
        for (int i = 0; i < 8; ++i) {
            int linear = i * 1024 + tid * 4;
            int r = linear >> 6;
            int c = linear & 63;
            const int32x4 wd = *reinterpret_cast<const int32x4*>(Wd + (size_t)(n0 + r) * I_DIM + k0 + c);
            float sc = Sd[(size_t)(n0 + r) * SStride + g];
            unsigned int d01 = (unsigned int)f2bf((float)(wd.x - 8) * sc) | ((unsigned int)f2bf((float)(wd.y - 8) * sc) << 16);
            unsigned int d23 = (unsigned int)f2bf((float)(wd.z - 8) * sc) | ((unsigned int)f2bf((float)(wd.w - 8) * sc) << 16);
            *reinterpret_cast<uint2*>(lB + r * 64 + c) = make_uint2(d01, d23);
        }
        __syncthreads();
#pragma unroll
        for (int ks = 0; ks < 2; ++ks) {
            const int koff = ks * 32 + (lane >> 4) * 8;
            bf16x8 af[4], bfr[4];
#pragma unroll
            for (int mi = 0; mi < 4; ++mi)
                af[mi] = *reinterpret_cast<const bf16x8*>(lA + (wr * 64 + mi * 16 + (lane & 15)) * 64 + koff);
#pragma unroll
            for (int ni = 0; ni < 4; ++ni)
                bfr[ni] = *reinterpret_cast<const bf16x8*>(lB + (wc * 64 + ni * 16 + (lane & 15)) * 64 + koff);
#pragma unroll
            for (int mi = 0; mi < 4; ++mi)
#pragma unroll
                for (int ni = 0; ni < 4; ++ni)
                    acc[mi][ni] = __builtin_amdgcn_mfma_f32_16x16x32_bf16(af[mi], bfr[ni], acc[mi][ni], 0, 0, 0);
        }
    }
#pragma unroll
    for (int mi = 0; mi < 4; ++mi)
#pragma unroll
        for (int ni = 0; ni < 4; ++ni) {
            const int col = n0 + wc * 64 + ni * 16 + (lane & 15);
#pragma unroll
            for (int r = 0; r < 4; ++r) {
                const int row = m0 + wr * 64 + mi * 16 + (lane >> 4) * 4 + r;
                Out[(size_t)row * D_DIM + col] = acc[mi][ni][r];
            }
        }
}

extern "C" void kernel_launch(void* const* d_in, const int* in_sizes, int n_in,
                              void* d_out, int out_size, void* d_ws, size_t ws_size,
                              hipStream_t stream) {
    const float* x       = (const float*)d_in[0];
    const int*   wq_gate = (const int*)d_in[1];
    const float* s_gate  = (const float*)d_in[2];
    const int*   wq_up   = (const int*)d_in[3];
    const float* s_up    = (const float*)d_in[4];
    const int*   wq_down = (const int*)d_in[5];
    const float* s_down  = (const float*)d_in[6];
    float* out = (float*)d_out;

    const size_t XR_E = (size_t)T_DIM * D_DIM;      // 16.8M
    const size_t H_E  = (size_t)T_DIM * I_DIM;      // 50.3M
    const size_t W_E  = (size_t)I_DIM * D_DIM;      // 50.3M (gate == up == down count)
    const size_t need = (XR_E + H_E + 2 * W_E) * sizeof(unsigned short);  // 335.5 MB

    unsigned short* xr = (unsigned short*)d_ws;
    unsigned short* h  = xr + XR_E;

    // 1) xr = hadamard(x) -> bf16
    {
        int ngroups = (int)(XR_E / 128);
        had_f32_to_bf16<<<dim3(ngroups / 4), dim3(256), 0, stream>>>(x, xr, ngroups);
    }

    if (ws_size >= need) {
        unsigned short* wgbf = h + H_E;
        unsigned short* wubf = wgbf + W_E;
        // 2) pre-dequant gate & up weights -> bf16
        {
            int total8 = (int)(W_E / 8);            // 6.29M threads
            dequant_w<<<dim3((total8 + 255) / 256), dim3(256), 0, stream>>>(wq_gate, s_gate, wgbf, D_DIM, total8);
            dequant_w<<<dim3((total8 + 255) / 256), dim3(256), 0, stream>>>(wq_up,   s_up,   wubf, D_DIM, total8);
        }
        // 3) h = silu(xr Wg^T) * (xr Wu^T)
        gemm_gateup_bf<<<dim3((T_DIM / 128) * (I_DIM / 128)), dim3(256), 0, stream>>>(xr, wgbf, wubf, h);
        // 4) h = hadamard(h) in-place
        {
            int ngroups = (int)(H_E / 128);
            had_bf16_inplace<<<dim3(ngroups / 4), dim3(256), 0, stream>>>(h, ngroups);
        }
        // 5) dequant down weights (reuse gate buffer; gateup GEMM already done, same stream)
        {
            int total8 = (int)(W_E / 8);
            dequant_w<<<dim3((total8 + 255) / 256), dim3(256), 0, stream>>>(wq_down, s_down, wgbf, I_DIM, total8);
        }
        // 6) out = hr Wd^T
        gemm_down_bf<<<dim3((T_DIM / 128) * (D_DIM / 128)), dim3(256), 0, stream>>>(h, wgbf, out);
    } else {
        // fallback: round-1 verified path (in-loop dequant)
        gemm_gateup_fb<<<dim3((T_DIM / 128) * (I_DIM / 128)), dim3(256), 0, stream>>>(
            xr, wq_gate, s_gate, wq_up, s_up, h);
        {
            int ngroups = (int)(H_E / 128);
            had_bf16_inplace<<<dim3(ngroups / 4), dim3(256), 0, stream>>>(h, ngroups);
        }
        gemm_down_fb<<<dim3((T_DIM / 128) * (D_DIM / 128)), dim3(256), 0, stream>>>(
            h, wq_down, s_down, out);
    }
}

// Round 3
// 1415.166 us; speedup vs baseline: 3.0283x; 1.2209x over previous
//
#include <hip/hip_runtime.h>
#include <hip/hip_bf16.h>
#include <cstdint>

#define T_DIM 4096
#define D_DIM 4096
#define I_DIM 12288
#define GRP   128

typedef __attribute__((ext_vector_type(8))) short bf16x8;   // MFMA A/B frag (8 bf16)
typedef __attribute__((ext_vector_type(4))) float f32x4;    // MFMA C/D frag
typedef __attribute__((ext_vector_type(4))) int   int32x4;

typedef __attribute__((address_space(3))) void lds_void;
typedef const __attribute__((address_space(1))) void gmem_void;

// f32 -> bf16 bits, round-to-nearest-even (finite inputs)
static __device__ __forceinline__ unsigned short f2bf(float f) {
    unsigned int u = __float_as_uint(f);
    u += 0x7FFFu + ((u >> 16) & 1u);
    return (unsigned short)(u >> 16);
}
static __device__ __forceinline__ float bf2f(unsigned short b) {
    return __uint_as_float(((unsigned int)b) << 16);
}

// ---------------- Hadamard (blockwise-128 FWHT), one wave per group, 2 elems/lane ----
__global__ void had_f32_to_bf16(const float* __restrict__ in, unsigned short* __restrict__ out,
                                int ngroups) {
    int gid = blockIdx.x * (blockDim.x >> 6) + (threadIdx.x >> 6);
    if (gid >= ngroups) return;
    int lane = threadIdx.x & 63;
    const float2 v2 = *reinterpret_cast<const float2*>(in + (size_t)gid * 128 + lane * 2);
    float v0 = v2.x, v1 = v2.y;
    { float t0 = v0 + v1, t1 = v0 - v1; v0 = t0; v1 = t1; }
#pragma unroll
    for (int m = 1; m <= 32; m <<= 1) {
        float b0 = __shfl_xor(v0, m);
        float b1 = __shfl_xor(v1, m);
        if (lane & m) { v0 = b0 - v0; v1 = b1 - v1; }
        else          { v0 = v0 + b0; v1 = v1 + b1; }
    }
    const float s = 0.08838834764831843f;  // 1/sqrt(128)
    unsigned int o = (unsigned int)f2bf(v0 * s) | ((unsigned int)f2bf(v1 * s) << 16);
    *reinterpret_cast<unsigned int*>(out + (size_t)gid * 128 + lane * 2) = o;
}

__global__ void had_bf16_inplace(unsigned short* __restrict__ buf, int ngroups) {
    int gid = blockIdx.x * (blockDim.x >> 6) + (threadIdx.x >> 6);
    if (gid >= ngroups) return;
    int lane = threadIdx.x & 63;
    unsigned int pv = *reinterpret_cast<const unsigned int*>(buf + (size_t)gid * 128 + lane * 2);
    float v0 = __uint_as_float((pv & 0xFFFFu) << 16);
    float v1 = __uint_as_float(pv & 0xFFFF0000u);
    { float t0 = v0 + v1, t1 = v0 - v1; v0 = t0; v1 = t1; }
#pragma unroll
    for (int m = 1; m <= 32; m <<= 1) {
        float b0 = __shfl_xor(v0, m);
        float b1 = __shfl_xor(v1, m);
        if (lane & m) { v0 = b0 - v0; v1 = b1 - v1; }
        else          { v0 = v0 + b0; v1 = v1 + b1; }
    }
    const float s = 0.08838834764831843f;
    unsigned int o = (unsigned int)f2bf(v0 * s) | ((unsigned int)f2bf(v1 * s) << 16);
    *reinterpret_cast<unsigned int*>(buf + (size_t)gid * 128 + lane * 2) = o;
}

// ---------------- weight dequant: int4-in-int32 [O,In] -> bf16 [O,In] ----------------
__global__ void dequant_w(const int* __restrict__ Wq, const float* __restrict__ S,
                          unsigned short* __restrict__ Wbf, int In, int total8) {
    int t = blockIdx.x * blockDim.x + threadIdx.x;
    if (t >= total8) return;
    size_t base = (size_t)t * 8;
    size_t row = base / (size_t)In;
    int col = (int)(base - row * (size_t)In);
    float sc = S[row * (size_t)(In >> 7) + (col >> 7)];
    const int32x4* p = reinterpret_cast<const int32x4*>(Wq + base);
    int32x4 a = p[0], b = p[1];
    float nsc = -8.0f * sc;
    unsigned int o0 = (unsigned int)f2bf((float)a.x * sc + nsc) |
                      ((unsigned int)f2bf((float)a.y * sc + nsc) << 16);
    unsigned int o1 = (unsigned int)f2bf((float)a.z * sc + nsc) |
                      ((unsigned int)f2bf((float)a.w * sc + nsc) << 16);
    unsigned int o2 = (unsigned int)f2bf((float)b.x * sc + nsc) |
                      ((unsigned int)f2bf((float)b.y * sc + nsc) << 16);
    unsigned int o3 = (unsigned int)f2bf((float)b.z * sc + nsc) |
                      ((unsigned int)f2bf((float)b.w * sc + nsc) << 16);
    *reinterpret_cast<uint4*>(Wbf + base) = make_uint4(o0, o1, o2, o3);
}

// =====================================================================================
// 256x256 8-phase GEMM (T1 XCD swizzle + T2 LDS XOR swizzle + T3/T4 counted vmcnt + T5)
// C[M,N] = A[M,K] @ W[N,K]^T,  bf16 inputs.
// MODE 0: store bf16.  MODE 1: h = silu(prevC)*acc, store bf16 in place.  MODE 2: f32.
// 8 waves (2M x 4N), per-wave 128x64 out, BK=64 as two k-halves of 32.
// LDS 128KB: [buf][A kh0|A kh1|B kh0|B kh1], each half-tile 256rows x 32k bf16 = 16KB.
// =====================================================================================

#define GBAR()  __builtin_amdgcn_s_barrier()
#define LGKM0() asm volatile("s_waitcnt lgkmcnt(0)" ::: "memory")
#define VM4()   asm volatile("s_waitcnt vmcnt(4)" ::: "memory")
#define VM0()   asm volatile("s_waitcnt vmcnt(0)" ::: "memory")

// stage step s of tile at k-offset kb into buffer bb: s=0:A-kh0 1:B-kh0 2:A-kh1 3:B-kh1
#define STAGE(bb, s, kb)                                                               \
  { const int kh_ = (s) >> 1;                                                          \
    const unsigned short* src_ = ((s) & 1) ? W : A;                                    \
    const int row0_ = ((s) & 1) ? n0 : m0;                                             \
    _Pragma("unroll")                                                                  \
    for (int i_ = 0; i_ < 2; ++i_) {                                                   \
      int j_ = i_ * 512 + tid;                                                         \
      int row_ = j_ >> 2;                                                              \
      int gs_ = (tid & 3) ^ ((row_ >> 1) & 3);                                         \
      const unsigned short* gp_ = src_ + (size_t)(row0_ + row_) * K + (kb) + kh_ * 32 + gs_ * 8; \
      unsigned short* lp_ = lds + ((bb) << 15) + (((s) & 1) << 14) + (kh_ << 13)       \
                            + (i_ * 512 + (wid << 6)) * 8;                             \
      __builtin_amdgcn_global_load_lds((gmem_void*)gp_, (lds_void*)lp_, 16, 0, 0);     \
    } }

#define LOADA(bb, kh, mg)                                                              \
  _Pragma("unroll")                                                                    \
  for (int mi_ = 0; mi_ < 4; ++mi_) {                                                  \
    int row_ = (wr << 7) + ((mg) * 4 + mi_) * 16 + (lane & 15);                        \
    af[mi_] = *reinterpret_cast<const bf16x8*>(lds + ((bb) << 15) + ((kh) << 13)       \
              + row_ * 32 + ((kc ^ ((row_ >> 1) & 3)) << 3));                          \
  }

#define LOADB(bb, kh)                                                                  \
  _Pragma("unroll")                                                                    \
  for (int ni_ = 0; ni_ < 4; ++ni_) {                                                  \
    int nr_ = (wc << 6) + ni_ * 16 + (lane & 15);                                      \
    bk[ni_] = *reinterpret_cast<const bf16x8*>(lds + ((bb) << 15) + 16384              \
              + ((kh) << 13) + nr_ * 32 + ((kc ^ ((nr_ >> 1) & 3)) << 3));             \
  }

#define MFMA16(mg)                                                                     \
  _Pragma("unroll")                                                                    \
  for (int mi_ = 0; mi_ < 4; ++mi_)                                                    \
  _Pragma("unroll")                                                                    \
  for (int ni_ = 0; ni_ < 4; ++ni_)                                                    \
    acc[(mg) * 4 + mi_][ni_] =                                                         \
      __builtin_amdgcn_mfma_f32_16x16x32_bf16(af[mi_], bk[ni_], acc[(mg) * 4 + mi_][ni_], 0, 0, 0);

template<int MODE>
__global__ __launch_bounds__(512, 2)
void gemm256(const unsigned short* __restrict__ A,      // [M,K] bf16
             const unsigned short* __restrict__ W,      // [N,K] bf16
             void* __restrict__ C, int M, int N, int K)
{
    __shared__ __align__(16) unsigned short lds[65536];  // 128 KB

    const int MT = M >> 8;
    const int nwg = gridDim.x;
    const int bid = blockIdx.x;
    const int cpx = nwg >> 3;                     // nwg % 8 == 0 in all our launches
    const int wg  = (bid & 7) * cpx + (bid >> 3); // bijective XCD swizzle
    const int m0 = (wg % MT) << 8;
    const int n0 = (wg / MT) << 8;

    const int tid  = threadIdx.x;
    const int lane = tid & 63;
    const int wid  = tid >> 6;
    const int wr = wid >> 2;                      // 0..1 (M half)
    const int wc = wid & 3;                       // 0..3 (N quarter)
    const int kc = lane >> 4;                     // 16B k-chunk within k-half

    f32x4 acc[8][4];
#pragma unroll
    for (int i = 0; i < 8; ++i)
#pragma unroll
        for (int j = 0; j < 4; ++j) acc[i][j] = (f32x4)0.0f;

    const int NT = K >> 6;

    // prologue: stage tile 0 into buf 0; wait for its kh0 halves (keep kh1 in flight)
    STAGE(0, 0, 0); STAGE(0, 1, 0); STAGE(0, 2, 0); STAGE(0, 3, 0);
    VM4();
    GBAR();

    for (int kt = 0; kt < NT; ++kt) {
        const int b  = kt & 1;
        const int kn = (kt + 1) << 6;
        const bool st = (kt + 1 < NT);
        bf16x8 af[4], bk[4];

        // ---- phase 1: kh0, m-group 0 ----
        LOADB(b, 0); LOADA(b, 0, 0);
        if (st) STAGE(b ^ 1, 0, kn);
        GBAR(); LGKM0();
        __builtin_amdgcn_s_setprio(1); MFMA16(0); __builtin_amdgcn_s_setprio(0);
        GBAR();
        // ---- phase 2: kh0, m-group 1 ----
        LOADA(b, 0, 1);
        if (st) STAGE(b ^ 1, 1, kn);
        GBAR(); LGKM0();
        __builtin_amdgcn_s_setprio(1); MFMA16(1); __builtin_amdgcn_s_setprio(0);
        if (st) { VM4(); } else { VM0(); }   // retire this tile's kh1 halves
        GBAR();
        // ---- phase 3: kh1, m-group 0 ----
        LOADB(b, 1); LOADA(b, 1, 0);
        if (st) STAGE(b ^ 1, 2, kn);
        GBAR(); LGKM0();
        __builtin_amdgcn_s_setprio(1); MFMA16(0); __builtin_amdgcn_s_setprio(0);
        GBAR();
        // ---- phase 4: kh1, m-group 1 ----
        LOADA(b, 1, 1);
        if (st) STAGE(b ^ 1, 3, kn);
        GBAR(); LGKM0();
        __builtin_amdgcn_s_setprio(1); MFMA16(1); __builtin_amdgcn_s_setprio(0);
        if (st) { VM4(); }                   // retire next tile's kh0 halves
        GBAR();
    }

    // ---- epilogue ----
#pragma unroll
    for (int mi = 0; mi < 8; ++mi)
#pragma unroll
        for (int ni = 0; ni < 4; ++ni) {
            const int col = n0 + (wc << 6) + ni * 16 + (lane & 15);
#pragma unroll
            for (int r = 0; r < 4; ++r) {
                const int row = m0 + (wr << 7) + mi * 16 + ((lane >> 4) << 2) + r;
                const size_t idx = (size_t)row * N + col;
                if (MODE == 2) {
                    ((float*)C)[idx] = acc[mi][ni][r];
                } else if (MODE == 0) {
                    ((unsigned short*)C)[idx] = f2bf(acc[mi][ni][r]);
                } else {
                    float g = bf2f(((unsigned short*)C)[idx]);
                    float u = acc[mi][ni][r];
                    float h = (g / (1.0f + __expf(-g))) * u;
                    ((unsigned short*)C)[idx] = f2bf(h);
                }
            }
        }
}

// ================== FALLBACK (round-1 verified): in-loop dequant GEMMs ==============
__global__ __launch_bounds__(256, 2)
void gemm_gateup_fb(const unsigned short* __restrict__ Xr,
                    const int* __restrict__ Wg, const float* __restrict__ Sg,
                    const int* __restrict__ Wu, const float* __restrict__ Su,
                    unsigned short* __restrict__ H)
{
    __shared__ __align__(16) unsigned short lA [128 * 64];
    __shared__ __align__(16) unsigned short lBg[128 * 64];
    __shared__ __align__(16) unsigned short lBu[128 * 64];
    const int MT = T_DIM / 128;
    const int bid = blockIdx.x;
    const int m0 = (bid % MT) * 128;
    const int n0 = (bid / MT) * 128;
    const int tid  = threadIdx.x;
    const int lane = tid & 63;
    const int wid  = tid >> 6;
    const int wr = wid >> 1, wc = wid & 1;
    f32x4 accG[4][4], accU[4][4];
#pragma unroll
    for (int i = 0; i < 4; ++i)
#pragma unroll
        for (int j = 0; j < 4; ++j) { accG[i][j] = (f32x4)0.0f; accU[i][j] = (f32x4)0.0f; }
    const int arow = lane >> 3;
    const int acol = (lane & 7) * 8;
    const int SStride = D_DIM / GRP;
    for (int k0 = 0; k0 < D_DIM; k0 += 64) {
        __syncthreads();
#pragma unroll
        for (int it = 0; it < 4; ++it) {
            int chunk = wid * 4 + it;
            const unsigned short* gp = Xr + (size_t)(m0 + chunk * 8 + arow) * D_DIM + k0 + acol;
            __builtin_amdgcn_global_load_lds((gmem_void*)gp, (lds_void*)(lA + chunk * 512), 16, 0, 0);
        }
        const int g = k0 >> 7;
#pragma unroll
        for (int i = 0; i < 8; ++i) {
            int linear = i * 1024 + tid * 4;
            int r = linear >> 6;
            int c = linear & 63;
            const int32x4 wg = *reinterpret_cast<const int32x4*>(Wg + (size_t)(n0 + r) * D_DIM + k0 + c);
            const int32x4 wu = *reinterpret_cast<const int32x4*>(Wu + (size_t)(n0 + r) * D_DIM + k0 + c);
            float scg = Sg[(size_t)(n0 + r) * SStride + g];
            float scu = Su[(size_t)(n0 + r) * SStride + g];
            unsigned int g01 = (unsigned int)f2bf((float)(wg.x - 8) * scg) | ((unsigned int)f2bf((float)(wg.y - 8) * scg) << 16);
            unsigned int g23 = (unsigned int)f2bf((float)(wg.z - 8) * scg) | ((unsigned int)f2bf((float)(wg.w - 8) * scg) << 16);
            unsigned int u01 = (unsigned int)f2bf((float)(wu.x - 8) * scu) | ((unsigned int)f2bf((float)(wu.y - 8) * scu) << 16);
            unsigned int u23 = (unsigned int)f2bf((float)(wu.z - 8) * scu) | ((unsigned int)f2bf((float)(wu.w - 8) * scu) << 16);
            *reinterpret_cast<uint2*>(lBg + r * 64 + c) = make_uint2(g01, g23);
            *reinterpret_cast<uint2*>(lBu + r * 64 + c) = make_uint2(u01, u23);
        }
        __syncthreads();
#pragma unroll
        for (int ks = 0; ks < 2; ++ks) {
            const int koff = ks * 32 + (lane >> 4) * 8;
            bf16x8 af[4], bg[4], bu[4];
#pragma unroll
            for (int mi = 0; mi < 4; ++mi)
                af[mi] = *reinterpret_cast<const bf16x8*>(lA + (wr * 64 + mi * 16 + (lane & 15)) * 64 + koff);
#pragma unroll
            for (int ni = 0; ni < 4; ++ni) {
                bg[ni] = *reinterpret_cast<const bf16x8*>(lBg + (wc * 64 + ni * 16 + (lane & 15)) * 64 + koff);
                bu[ni] = *reinterpret_cast<const bf16x8*>(lBu + (wc * 64 + ni * 16 + (lane & 15)) * 64 + koff);
            }
#pragma unroll
            for (int mi = 0; mi < 4; ++mi)
#pragma unroll
                for (int ni = 0; ni < 4; ++ni) {
                    accG[mi][ni] = __builtin_amdgcn_mfma_f32_16x16x32_bf16(af[mi], bg[ni], accG[mi][ni], 0, 0, 0);
                    accU[mi][ni] = __builtin_amdgcn_mfma_f32_16x16x32_bf16(af[mi], bu[ni], accU[mi][ni], 0, 0, 0);
                }
        }
    }
#pragma unroll
    for (int mi = 0; mi < 4; ++mi)
#pragma unroll
        for (int ni = 0; ni < 4; ++ni) {
            const int col = n0 + wc * 64 + ni * 16 + (lane & 15);
#pragma unroll
            for (int r = 0; r < 4; ++r) {
                const int row = m0 + wr * 64 + mi * 16 + (lane >> 4) * 4 + r;
                float gv = accG[mi][ni][r];
                float uv = accU[mi][ni][r];
                float hv = (gv / (1.0f + __expf(-gv))) * uv;
                H[(size_t)row * I_DIM + col] = f2bf(hv);
            }
        }
}

__global__ __launch_bounds__(256, 2)
void gemm_down_fb(const unsigned short* __restrict__ Hr,
                  const int* __restrict__ Wd, const float* __restrict__ Sd,
                  float* __restrict__ Out)
{
    __shared__ __align__(16) unsigned short lA[128 * 64];
    __shared__ __align__(16) unsigned short lB[128 * 64];
    const int MT = T_DIM / 128;
    const int bid = blockIdx.x;
    const int m0 = (bid % MT) * 128;
    const int n0 = (bid / MT) * 128;
    const int tid  = threadIdx.x;
    const int lane = tid & 63;
    const int wid  = tid >> 6;
    const int wr = wid >> 1, wc = wid & 1;
    f32x4 acc[4][4];
#pragma unroll
    for (int i = 0; i < 4; ++i)
#pragma unroll
        for (int j = 0; j < 4; ++j) acc[i][j] = (f32x4)0.0f;
    const int arow = lane >> 3;
    const int acol = (lane & 7) * 8;
    const int SStride = I_DIM / GRP;
    for (int k0 = 0; k0 < I_DIM; k0 += 64) {
        __syncthreads();
#pragma unroll
        for (int it = 0; it < 4; ++it) {
            int chunk = wid * 4 + it;
            const unsigned short* gp = Hr + (size_t)(m0 + chunk * 8 + arow) * I_DIM + k0 + acol;
            __builtin_amdgcn_global_load_lds((gmem_void*)gp, (lds_void*)(lA + chunk * 512), 16, 0, 0);
        }
        const int g = k0 >> 7;
#pragma unroll
        for (int i = 0; i < 8; ++i) {
            int linear = i * 1024 + tid * 4;
            int r = linear >> 6;
            int c = linear & 63;
            const int32x4 wd = *reinterpret_cast<const int32x4*>(Wd + (size_t)(n0 + r) * I_DIM + k0 + c);
            float sc = Sd[(size_t)(n0 + r) * SStride + g];
            unsigned int d01 = (unsigned int)f2bf((float)(wd.x - 8) * sc) | ((unsigned int)f2bf((float)(wd.y - 8) * sc) << 16);
            unsigned int d23 = (unsigned int)f2bf((float)(wd.z - 8) * sc) | ((unsigned int)f2bf((float)(wd.w - 8) * sc) << 16);
            *reinterpret_cast<uint2*>(lB + r * 64 + c) = make_uint2(d01, d23);
        }
        __syncthreads();
#pragma unroll
        for (int ks = 0; ks < 2; ++ks) {
            const int koff = ks * 32 + (lane >> 4) * 8;
            bf16x8 af[4], bfr[4];
#pragma unroll
            for (int mi = 0; mi < 4; ++mi)
                af[mi] = *reinterpret_cast<const bf16x8*>(lA + (wr * 64 + mi * 16 + (lane & 15)) * 64 + koff);
#pragma unroll
            for (int ni = 0; ni < 4; ++ni)
                bfr[ni] = *reinterpret_cast<const bf16x8*>(lB + (wc * 64 + ni * 16 + (lane & 15)) * 64 + koff);
#pragma unroll
            for (int mi = 0; mi < 4; ++mi)
#pragma unroll
                for (int ni = 0; ni < 4; ++ni)
                    acc[mi][ni] = __builtin_amdgcn_mfma_f32_16x16x32_bf16(af[mi], bfr[ni], acc[mi][ni], 0, 0, 0);
        }
    }
#pragma unroll
    for (int mi = 0; mi < 4; ++mi)
#pragma unroll
        for (int ni = 0; ni < 4; ++ni) {
            const int col = n0 + wc * 64 + ni * 16 + (lane & 15);
#pragma unroll
            for (int r = 0; r < 4; ++r) {
                const int row = m0 + wr * 64 + mi * 16 + (lane >> 4) * 4 + r;
                Out[(size_t)row * D_DIM + col] = acc[mi][ni][r];
            }
        }
}

extern "C" void kernel_launch(void* const* d_in, const int* in_sizes, int n_in,
                              void* d_out, int out_size, void* d_ws, size_t ws_size,
                              hipStream_t stream) {
    const float* x       = (const float*)d_in[0];
    const int*   wq_gate = (const int*)d_in[1];
    const float* s_gate  = (const float*)d_in[2];
    const int*   wq_up   = (const int*)d_in[3];
    const float* s_up    = (const float*)d_in[4];
    const int*   wq_down = (const int*)d_in[5];
    const float* s_down  = (const float*)d_in[6];
    float* out = (float*)d_out;

    const size_t XR_E = (size_t)T_DIM * D_DIM;      // 16.8M
    const size_t H_E  = (size_t)T_DIM * I_DIM;      // 50.3M
    const size_t W_E  = (size_t)I_DIM * D_DIM;      // 50.3M
    const size_t need = (XR_E + H_E + 2 * W_E) * sizeof(unsigned short);  // 335.5 MB

    unsigned short* xr = (unsigned short*)d_ws;
    unsigned short* h  = xr + XR_E;

    // 1) xr = hadamard(x) -> bf16
    {
        int ngroups = (int)(XR_E / 128);
        had_f32_to_bf16<<<dim3(ngroups / 4), dim3(256), 0, stream>>>(x, xr, ngroups);
    }

    if (ws_size >= need) {
        unsigned short* wgbf = h + H_E;
        unsigned short* wubf = wgbf + W_E;
        int total8 = (int)(W_E / 8);
        // 2) pre-dequant gate & up weights -> bf16
        dequant_w<<<dim3((total8 + 255) / 256), dim3(256), 0, stream>>>(wq_gate, s_gate, wgbf, D_DIM, total8);
        dequant_w<<<dim3((total8 + 255) / 256), dim3(256), 0, stream>>>(wq_up,   s_up,   wubf, D_DIM, total8);
        // 3) gate = xr @ Wg^T  (bf16, into h)
        gemm256<0><<<dim3((T_DIM / 256) * (I_DIM / 256)), dim3(512), 0, stream>>>(
            xr, wgbf, (void*)h, T_DIM, I_DIM, D_DIM);
        // 4) h = silu(gate) * (xr @ Wu^T)   (fused epilogue, in place over h)
        gemm256<1><<<dim3((T_DIM / 256) * (I_DIM / 256)), dim3(512), 0, stream>>>(
            xr, wubf, (void*)h, T_DIM, I_DIM, D_DIM);
        // 5) h = hadamard(h) in place
        {
            int ngroups = (int)(H_E / 128);
            had_bf16_inplace<<<dim3(ngroups / 4), dim3(256), 0, stream>>>(h, ngroups);
        }
        // 6) dequant down weights (reuse gate buffer)
        dequant_w<<<dim3((total8 + 255) / 256), dim3(256), 0, stream>>>(wq_down, s_down, wgbf, I_DIM, total8);
        // 7) out = h @ Wd^T  (f32)
        gemm256<2><<<dim3((T_DIM / 256) * (D_DIM / 256)), dim3(512), 0, stream>>>(
            h, wgbf, (void*)out, T_DIM, D_DIM, I_DIM);
    } else {
        // fallback: round-1 verified path (in-loop dequant)
        gemm_gateup_fb<<<dim3((T_DIM / 128) * (I_DIM / 128)), dim3(256), 0, stream>>>(
            xr, wq_gate, s_gate, wq_up, s_up, h);
        {
            int ngroups = (int)(H_E / 128);
            had_bf16_inplace<<<dim3(ngroups / 4), dim3(256), 0, stream>>>(h, ngroups);
        }
        gemm_down_fb<<<dim3((T_DIM / 128) * (D_DIM / 128)), dim3(256), 0, stream>>>(
            h, wq_down, s_down, out);
    }
}

// Round 4
// 1279.933 us; speedup vs baseline: 3.3483x; 1.1057x over previous
//
#include <hip/hip_runtime.h>
#include <hip/hip_bf16.h>
#include <cstdint>

#define T_DIM 4096
#define D_DIM 4096
#define I_DIM 12288
#define GRP   128

typedef __attribute__((ext_vector_type(8))) short bf16x8;   // MFMA A/B frag (8 bf16)
typedef __attribute__((ext_vector_type(4))) float f32x4;    // MFMA C/D frag
typedef __attribute__((ext_vector_type(4))) int   int32x4;

typedef __attribute__((address_space(3))) void lds_void;
typedef const __attribute__((address_space(1))) void gmem_void;

// f32 -> bf16 bits, round-to-nearest-even (finite inputs)
static __device__ __forceinline__ unsigned short f2bf(float f) {
    unsigned int u = __float_as_uint(f);
    u += 0x7FFFu + ((u >> 16) & 1u);
    return (unsigned short)(u >> 16);
}
static __device__ __forceinline__ float bf2f(unsigned short b) {
    return __uint_as_float(((unsigned int)b) << 16);
}

// ---------------- Hadamard (blockwise-128 FWHT), one wave per group, 2 elems/lane ----
__global__ void had_f32_to_bf16(const float* __restrict__ in, unsigned short* __restrict__ out,
                                int ngroups) {
    int gid = blockIdx.x * (blockDim.x >> 6) + (threadIdx.x >> 6);
    if (gid >= ngroups) return;
    int lane = threadIdx.x & 63;
    const float2 v2 = *reinterpret_cast<const float2*>(in + (size_t)gid * 128 + lane * 2);
    float v0 = v2.x, v1 = v2.y;
    { float t0 = v0 + v1, t1 = v0 - v1; v0 = t0; v1 = t1; }
#pragma unroll
    for (int m = 1; m <= 32; m <<= 1) {
        float b0 = __shfl_xor(v0, m);
        float b1 = __shfl_xor(v1, m);
        if (lane & m) { v0 = b0 - v0; v1 = b1 - v1; }
        else          { v0 = v0 + b0; v1 = v1 + b1; }
    }
    const float s = 0.08838834764831843f;  // 1/sqrt(128)
    unsigned int o = (unsigned int)f2bf(v0 * s) | ((unsigned int)f2bf(v1 * s) << 16);
    *reinterpret_cast<unsigned int*>(out + (size_t)gid * 128 + lane * 2) = o;
}

__global__ void had_bf16_inplace(unsigned short* __restrict__ buf, int ngroups) {
    int gid = blockIdx.x * (blockDim.x >> 6) + (threadIdx.x >> 6);
    if (gid >= ngroups) return;
    int lane = threadIdx.x & 63;
    unsigned int pv = *reinterpret_cast<const unsigned int*>(buf + (size_t)gid * 128 + lane * 2);
    float v0 = __uint_as_float((pv & 0xFFFFu) << 16);
    float v1 = __uint_as_float(pv & 0xFFFF0000u);
    { float t0 = v0 + v1, t1 = v0 - v1; v0 = t0; v1 = t1; }
#pragma unroll
    for (int m = 1; m <= 32; m <<= 1) {
        float b0 = __shfl_xor(v0, m);
        float b1 = __shfl_xor(v1, m);
        if (lane & m) { v0 = b0 - v0; v1 = b1 - v1; }
        else          { v0 = v0 + b0; v1 = v1 + b1; }
    }
    const float s = 0.08838834764831843f;
    unsigned int o = (unsigned int)f2bf(v0 * s) | ((unsigned int)f2bf(v1 * s) << 16);
    *reinterpret_cast<unsigned int*>(buf + (size_t)gid * 128 + lane * 2) = o;
}

// ---------------- weight dequant: int4-in-int32 [O,In] -> bf16 [O,In] ----------------
__global__ void dequant_w(const int* __restrict__ Wq, const float* __restrict__ S,
                          unsigned short* __restrict__ Wbf, int In, int total8) {
    int t = blockIdx.x * blockDim.x + threadIdx.x;
    if (t >= total8) return;
    size_t base = (size_t)t * 8;
    size_t row = base / (size_t)In;
    int col = (int)(base - row * (size_t)In);
    float sc = S[row * (size_t)(In >> 7) + (col >> 7)];
    const int32x4* p = reinterpret_cast<const int32x4*>(Wq + base);
    int32x4 a = p[0], b = p[1];
    float nsc = -8.0f * sc;
    unsigned int o0 = (unsigned int)f2bf((float)a.x * sc + nsc) |
                      ((unsigned int)f2bf((float)a.y * sc + nsc) << 16);
    unsigned int o1 = (unsigned int)f2bf((float)a.z * sc + nsc) |
                      ((unsigned int)f2bf((float)a.w * sc + nsc) << 16);
    unsigned int o2 = (unsigned int)f2bf((float)b.x * sc + nsc) |
                      ((unsigned int)f2bf((float)b.y * sc + nsc) << 16);
    unsigned int o3 = (unsigned int)f2bf((float)b.z * sc + nsc) |
                      ((unsigned int)f2bf((float)b.w * sc + nsc) << 16);
    *reinterpret_cast<uint4*>(Wbf + base) = make_uint4(o0, o1, o2, o3);
}

// =====================================================================================
// 256x256 GEMM, 2 K-tiles per iteration, 8 phases, deep-prefetch counted vmcnt.
// C[M,N] = A[M,K] @ W[N,K]^T, bf16 in. MODE 0: bf16 out; 1: silu(C)*acc in place; 2: f32.
// 8 waves (2M x 4N); per-wave 128x64; per phase: one C-quadrant (2m x 4n) x K=64.
// LDS per buf: A[256][64] + B[256][64] bf16 = 64KB; 2 bufs = 128KB.
// Row = 128B = 8 chunks of 16B; LDS chunk c holds global chunk c ^ (row&7) (T2).
// Stage order (iter j, tiles a=2j,a+1): ph1-2 A(a+1), ph3-4 B(a+2), ph5-6 A(a+2),
// ph7-8 B(a+3). vmcnt(4) at ph4/ph8 retires loads issued 4-7 phases earlier.
// =====================================================================================

#define GBAR()  __builtin_amdgcn_s_barrier()
#define LGKM0() asm volatile("s_waitcnt lgkmcnt(0)" ::: "memory")
#define VMW(n)  asm volatile("s_waitcnt vmcnt(" #n ")" ::: "memory")
#define P1()    __builtin_amdgcn_s_setprio(1)
#define P0()    __builtin_amdgcn_s_setprio(0)

// stage half-tile: buffer bb, mat (0=A,1=B), M-half h, k-base kb. 2 x global_load_lds.
#define STG(bb, mat, h, kb)                                                            \
  { _Pragma("unroll")                                                                  \
    for (int i_ = 0; i_ < 2; ++i_) {                                                   \
      const int rl_ = (h) * 128 + i_ * 64 + (tid >> 3);                                \
      const int gs_ = (tid & 7) ^ ((tid >> 3) & 7);                                    \
      const unsigned short* gp_ = ((mat) ? W : A) +                                    \
          (size_t)(((mat) ? n0 : m0) + rl_) * K + (kb) + gs_ * 8;                      \
      unsigned short* lp_ = lds + (bb) * 32768 + (mat) * 16384 +                       \
          ((h) * 128 + i_ * 64 + wid * 8) * 64;                                        \
      __builtin_amdgcn_global_load_lds((gmem_void*)gp_, (lds_void*)lp_, 16, 0, 0);     \
    } }

// per-phase A frags: quadrant q (2 m-frags), both k-subs
#define LDA(bb, q)                                                                     \
  _Pragma("unroll")                                                                    \
  for (int mi_ = 0; mi_ < 2; ++mi_)                                                    \
  _Pragma("unroll")                                                                    \
  for (int ks_ = 0; ks_ < 2; ++ks_) {                                                  \
    int r_ = wr * 128 + ((q) * 2 + mi_) * 16 + (lane & 15);                            \
    int c_ = ks_ * 4 + kc;                                                             \
    af[mi_][ks_] = *reinterpret_cast<const bf16x8*>(                                   \
        lds + (bb) * 32768 + r_ * 64 + ((c_ ^ (r_ & 7)) << 3));                        \
  }

// per-K-tile B frags: 4 n-frags x 2 k-subs (live across 4 phases)
#define LDB(bb)                                                                        \
  _Pragma("unroll")                                                                    \
  for (int ni_ = 0; ni_ < 4; ++ni_)                                                    \
  _Pragma("unroll")                                                                    \
  for (int ks_ = 0; ks_ < 2; ++ks_) {                                                  \
    int r_ = wc * 64 + ni_ * 16 + (lane & 15);                                         \
    int c_ = ks_ * 4 + kc;                                                             \
    bk[ni_][ks_] = *reinterpret_cast<const bf16x8*>(                                   \
        lds + (bb) * 32768 + 16384 + r_ * 64 + ((c_ ^ (r_ & 7)) << 3));                \
  }

#define MF16(q)                                                                        \
  _Pragma("unroll")                                                                    \
  for (int ks_ = 0; ks_ < 2; ++ks_)                                                    \
  _Pragma("unroll")                                                                    \
  for (int mi_ = 0; mi_ < 2; ++mi_)                                                    \
  _Pragma("unroll")                                                                    \
  for (int ni_ = 0; ni_ < 4; ++ni_)                                                    \
    acc[(q) * 2 + mi_][ni_] = __builtin_amdgcn_mfma_f32_16x16x32_bf16(                 \
        af[mi_][ks_], bk[ni_][ks_], acc[(q) * 2 + mi_][ni_], 0, 0, 0);

template<int MODE>
__global__ __launch_bounds__(512, 2)
void gemm256(const unsigned short* __restrict__ A,      // [M,K] bf16
             const unsigned short* __restrict__ W,      // [N,K] bf16
             void* __restrict__ C, int M, int N, int K)
{
    __shared__ __align__(16) unsigned short lds[65536];  // 128 KB

    const int MT = M >> 8;
    const int nwg = gridDim.x;
    const int bid = blockIdx.x;
    const int cpx = nwg >> 3;                     // nwg % 8 == 0 in all our launches
    const int wg  = (bid & 7) * cpx + (bid >> 3); // bijective XCD swizzle
    const int m0 = (wg % MT) << 8;
    const int n0 = (wg / MT) << 8;

    const int tid  = threadIdx.x;
    const int lane = tid & 63;
    const int wid  = tid >> 6;
    const int wr = wid >> 2;                      // 0..1 (M half)
    const int wc = wid & 3;                       // 0..3 (N quarter)
    const int kc = lane >> 4;                     // 16B k-chunk selector

    f32x4 acc[8][4];
#pragma unroll
    for (int i = 0; i < 8; ++i)
#pragma unroll
        for (int j = 0; j < 4; ++j) acc[i][j] = (f32x4)0.0f;

    const int NT = K >> 6;                        // K-tiles (even: 64 or 192)
    const int J  = NT >> 1;                       // iterations

    // ---- prologue: tile0 (A+B) and tile1 (B); retire tile0, keep B(1) in flight ----
    STG(0, 0, 0, 0); STG(0, 0, 1, 0); STG(0, 1, 0, 0); STG(0, 1, 1, 0);
    STG(1, 1, 0, 64); STG(1, 1, 1, 64);
    VMW(4);
    GBAR();

    bf16x8 af[2][2], bk[4][2];

    for (int j = 0; j < J - 1; ++j) {
        const int ka  = (j << 7);           // tile a = 2j     (buf0)
        const int kb1 = ka + 64;            // tile a+1        (buf1)
        const int ka2 = ka + 128;           // tile a+2
        const int ka3 = ka + 192;           // tile a+3
        // ---- ph1: tile a, q0 ----
        LDB(0); LDA(0, 0); STG(1, 0, 0, kb1);
        GBAR(); LGKM0(); P1(); MF16(0); P0(); GBAR();
        // ---- ph2: q1 ----
        LDA(0, 1); STG(1, 0, 1, kb1);
        GBAR(); LGKM0(); P1(); MF16(1); P0(); GBAR();
        // ---- ph3: q2 ----
        LDA(0, 2); STG(0, 1, 0, ka2);
        GBAR(); LGKM0(); P1(); MF16(2); P0(); GBAR();
        // ---- ph4: q3 ----
        LDA(0, 3); STG(0, 1, 1, ka2);
        GBAR(); LGKM0(); P1(); MF16(3); P0(); VMW(4); GBAR();
        // ---- ph5: tile a+1, q0 ----
        LDB(1); LDA(1, 0); STG(0, 0, 0, ka2);
        GBAR(); LGKM0(); P1(); MF16(0); P0(); GBAR();
        // ---- ph6: q1 ----
        LDA(1, 1); STG(0, 0, 1, ka2);
        GBAR(); LGKM0(); P1(); MF16(1); P0(); GBAR();
        // ---- ph7: q2 ----
        LDA(1, 2); STG(1, 1, 0, ka3);
        GBAR(); LGKM0(); P1(); MF16(2); P0(); GBAR();
        // ---- ph8: q3 ----
        LDA(1, 3); STG(1, 1, 1, ka3);
        GBAR(); LGKM0(); P1(); MF16(3); P0(); VMW(4); GBAR();
    }

    // ---- peeled final iteration (tiles NT-2, NT-1): stage only A(NT-1) ----
    {
        const int kb1 = ((NT - 1) << 6);
        LDB(0); LDA(0, 0); STG(1, 0, 0, kb1);
        GBAR(); LGKM0(); P1(); MF16(0); P0(); GBAR();
        LDA(0, 1); STG(1, 0, 1, kb1);
        GBAR(); LGKM0(); P1(); MF16(1); P0(); GBAR();
        LDA(0, 2);
        GBAR(); LGKM0(); P1(); MF16(2); P0(); GBAR();
        LDA(0, 3);
        GBAR(); LGKM0(); P1(); MF16(3); P0(); VMW(0); GBAR();
        LDB(1); LDA(1, 0);
        GBAR(); LGKM0(); P1(); MF16(0); P0(); GBAR();
        LDA(1, 1);
        GBAR(); LGKM0(); P1(); MF16(1); P0(); GBAR();
        LDA(1, 2);
        GBAR(); LGKM0(); P1(); MF16(2); P0(); GBAR();
        LDA(1, 3);
        GBAR(); LGKM0(); P1(); MF16(3); P0(); GBAR();
    }

    // ---- epilogue ----
#pragma unroll
    for (int mi = 0; mi < 8; ++mi)
#pragma unroll
        for (int ni = 0; ni < 4; ++ni) {
            const int col = n0 + (wc << 6) + ni * 16 + (lane & 15);
#pragma unroll
            for (int r = 0; r < 4; ++r) {
                const int row = m0 + (wr << 7) + mi * 16 + ((lane >> 4) << 2) + r;
                const size_t idx = (size_t)row * N + col;
                if (MODE == 2) {
                    ((float*)C)[idx] = acc[mi][ni][r];
                } else if (MODE == 0) {
                    ((unsigned short*)C)[idx] = f2bf(acc[mi][ni][r]);
                } else {
                    float g = bf2f(((unsigned short*)C)[idx]);
                    float u = acc[mi][ni][r];
                    float h = (g / (1.0f + __expf(-g))) * u;
                    ((unsigned short*)C)[idx] = f2bf(h);
                }
            }
        }
}

// ================== FALLBACK (round-1 verified): in-loop dequant GEMMs ==============
__global__ __launch_bounds__(256, 2)
void gemm_gateup_fb(const unsigned short* __restrict__ Xr,
                    const int* __restrict__ Wg, const float* __restrict__ Sg,
                    const int* __restrict__ Wu, const float* __restrict__ Su,
                    unsigned short* __restrict__ H)
{
    __shared__ __align__(16) unsigned short lA [128 * 64];
    __shared__ __align__(16) unsigned short lBg[128 * 64];
    __shared__ __align__(16) unsigned short lBu[128 * 64];
    const int MT = T_DIM / 128;
    const int bid = blockIdx.x;
    const int m0 = (bid % MT) * 128;
    const int n0 = (bid / MT) * 128;
    const int tid  = threadIdx.x;
    const int lane = tid & 63;
    const int wid  = tid >> 6;
    const int wr = wid >> 1, wc = wid & 1;
    f32x4 accG[4][4], accU[4][4];
#pragma unroll
    for (int i = 0; i < 4; ++i)
#pragma unroll
        for (int j = 0; j < 4; ++j) { accG[i][j] = (f32x4)0.0f; accU[i][j] = (f32x4)0.0f; }
    const int arow = lane >> 3;
    const int acol = (lane & 7) * 8;
    const int SStride = D_DIM / GRP;
    for (int k0 = 0; k0 < D_DIM; k0 += 64) {
        __syncthreads();
#pragma unroll
        for (int it = 0; it < 4; ++it) {
            int chunk = wid * 4 + it;
            const unsigned short* gp = Xr + (size_t)(m0 + chunk * 8 + arow) * D_DIM + k0 + acol;
            __builtin_amdgcn_global_load_lds((gmem_void*)gp, (lds_void*)(lA + chunk * 512), 16, 0, 0);
        }
        const int g = k0 >> 7;
#pragma unroll
        for (int i = 0; i < 8; ++i) {
            int linear = i * 1024 + tid * 4;
            int r = linear >> 6;
            int c = linear & 63;
            const int32x4 wg = *reinterpret_cast<const int32x4*>(Wg + (size_t)(n0 + r) * D_DIM + k0 + c);
            const int32x4 wu = *reinterpret_cast<const int32x4*>(Wu + (size_t)(n0 + r) * D_DIM + k0 + c);
            float scg = Sg[(size_t)(n0 + r) * SStride + g];
            float scu = Su[(size_t)(n0 + r) * SStride + g];
            unsigned int g01 = (unsigned int)f2bf((float)(wg.x - 8) * scg) | ((unsigned int)f2bf((float)(wg.y - 8) * scg) << 16);
            unsigned int g23 = (unsigned int)f2bf((float)(wg.z - 8) * scg) | ((unsigned int)f2bf((float)(wg.w - 8) * scg) << 16);
            unsigned int u01 = (unsigned int)f2bf((float)(wu.x - 8) * scu) | ((unsigned int)f2bf((float)(wu.y - 8) * scu) << 16);
            unsigned int u23 = (unsigned int)f2bf((float)(wu.z - 8) * scu) | ((unsigned int)f2bf((float)(wu.w - 8) * scu) << 16);
            *reinterpret_cast<uint2*>(lBg + r * 64 + c) = make_uint2(g01, g23);
            *reinterpret_cast<uint2*>(lBu + r * 64 + c) = make_uint2(u01, u23);
        }
        __syncthreads();
#pragma unroll
        for (int ks = 0; ks < 2; ++ks) {
            const int koff = ks * 32 + (lane >> 4) * 8;
            bf16x8 af[4], bg[4], bu[4];
#pragma unroll
            for (int mi = 0; mi < 4; ++mi)
                af[mi] = *reinterpret_cast<const bf16x8*>(lA + (wr * 64 + mi * 16 + (lane & 15)) * 64 + koff);
#pragma unroll
            for (int ni = 0; ni < 4; ++ni) {
                bg[ni] = *reinterpret_cast<const bf16x8*>(lBg + (wc * 64 + ni * 16 + (lane & 15)) * 64 + koff);
                bu[ni] = *reinterpret_cast<const bf16x8*>(lBu + (wc * 64 + ni * 16 + (lane & 15)) * 64 + koff);
            }
#pragma unroll
            for (int mi = 0; mi < 4; ++mi)
#pragma unroll
                for (int ni = 0; ni < 4; ++ni) {
                    accG[mi][ni] = __builtin_amdgcn_mfma_f32_16x16x32_bf16(af[mi], bg[ni], accG[mi][ni], 0, 0, 0);
                    accU[mi][ni] = __builtin_amdgcn_mfma_f32_16x16x32_bf16(af[mi], bu[ni], accU[mi][ni], 0, 0, 0);
                }
        }
    }
#pragma unroll
    for (int mi = 0; mi < 4; ++mi)
#pragma unroll
        for (int ni = 0; ni < 4; ++ni) {
            const int col = n0 + wc * 64 + ni * 16 + (lane & 15);
#pragma unroll
            for (int r = 0; r < 4; ++r) {
                const int row = m0 + wr * 64 + mi * 16 + (lane >> 4) * 4 + r;
                float gv = accG[mi][ni][r];
                float uv = accU[mi][ni][r];
                float hv = (gv / (1.0f + __expf(-gv))) * uv;
                H[(size_t)row * I_DIM + col] = f2bf(hv);
            }
        }
}

__global__ __launch_bounds__(256, 2)
void gemm_down_fb(const unsigned short* __restrict__ Hr,
                  const int* __restrict__ Wd, const float* __restrict__ Sd,
                  float* __restrict__ Out)
{
    __shared__ __align__(16) unsigned short lA[128 * 64];
    __shared__ __align__(16) unsigned short lB[128 * 64];
    const int MT = T_DIM / 128;
    const int bid = blockIdx.x;
    const int m0 = (bid % MT) * 128;
    const int n0 = (bid / MT) * 128;
    const int tid  = threadIdx.x;
    const int lane = tid & 63;
    const int wid  = tid >> 6;
    const int wr = wid >> 1, wc = wid & 1;
    f32x4 acc[4][4];
#pragma unroll
    for (int i = 0; i < 4; ++i)
#pragma unroll
        for (int j = 0; j < 4; ++j) acc[i][j] = (f32x4)0.0f;
    const int arow = lane >> 3;
    const int acol = (lane & 7) * 8;
    const int SStride = I_DIM / GRP;
    for (int k0 = 0; k0 < I_DIM; k0 += 64) {
        __syncthreads();
#pragma unroll
        for (int it = 0; it < 4; ++it) {
            int chunk = wid * 4 + it;
            const unsigned short* gp = Hr + (size_t)(m0 + chunk * 8 + arow) * I_DIM + k0 + acol;
            __builtin_amdgcn_global_load_lds((gmem_void*)gp, (lds_void*)(lA + chunk * 512), 16, 0, 0);
        }
        const int g = k0 >> 7;
#pragma unroll
        for (int i = 0; i < 8; ++i) {
            int linear = i * 1024 + tid * 4;
            int r = linear >> 6;
            int c = linear & 63;
            const int32x4 wd = *reinterpret_cast<const int32x4*>(Wd + (size_t)(n0 + r) * I_DIM + k0 + c);
            float sc = Sd[(size_t)(n0 + r) * SStride + g];
            unsigned int d01 = (unsigned int)f2bf((float)(wd.x - 8) * sc) | ((unsigned int)f2bf((float)(wd.y - 8) * sc) << 16);
            unsigned int d23 = (unsigned int)f2bf((float)(wd.z - 8) * sc) | ((unsigned int)f2bf((float)(wd.w - 8) * sc) << 16);
            *reinterpret_cast<uint2*>(lB + r * 64 + c) = make_uint2(d01, d23);
        }
        __syncthreads();
#pragma unroll
        for (int ks = 0; ks < 2; ++ks) {
            const int koff = ks * 32 + (lane >> 4) * 8;
            bf16x8 af[4], bfr[4];
#pragma unroll
            for (int mi = 0; mi < 4; ++mi)
                af[mi] = *reinterpret_cast<const bf16x8*>(lA + (wr * 64 + mi * 16 + (lane & 15)) * 64 + koff);
#pragma unroll
            for (int ni = 0; ni < 4; ++ni)
                bfr[ni] = *reinterpret_cast<const bf16x8*>(lB + (wc * 64 + ni * 16 + (lane & 15)) * 64 + koff);
#pragma unroll
            for (int mi = 0; mi < 4; ++mi)
#pragma unroll
                for (int ni = 0; ni < 4; ++ni)
                    acc[mi][ni] = __builtin_amdgcn_mfma_f32_16x16x32_bf16(af[mi], bfr[ni], acc[mi][ni], 0, 0, 0);
        }
    }
#pragma unroll
    for (int mi = 0; mi < 4; ++mi)
#pragma unroll
        for (int ni = 0; ni < 4; ++ni) {
            const int col = n0 + wc * 64 + ni * 16 + (lane & 15);
#pragma unroll
            for (int r = 0; r < 4; ++r) {
                const int row = m0 + wr * 64 + mi * 16 + (lane >> 4) * 4 + r;
                Out[(size_t)row * D_DIM + col] = acc[mi][ni][r];
            }
        }
}

extern "C" void kernel_launch(void* const* d_in, const int* in_sizes, int n_in,
                              void* d_out, int out_size, void* d_ws, size_t ws_size,
                              hipStream_t stream) {
    const float* x       = (const float*)d_in[0];
    const int*   wq_gate = (const int*)d_in[1];
    const float* s_gate  = (const float*)d_in[2];
    const int*   wq_up   = (const int*)d_in[3];
    const float* s_up    = (const float*)d_in[4];
    const int*   wq_down = (const int*)d_in[5];
    const float* s_down  = (const float*)d_in[6];
    float* out = (float*)d_out;

    const size_t XR_E = (size_t)T_DIM * D_DIM;      // 16.8M
    const size_t H_E  = (size_t)T_DIM * I_DIM;      // 50.3M
    const size_t W_E  = (size_t)I_DIM * D_DIM;      // 50.3M
    const size_t need = (XR_E + H_E + 2 * W_E) * sizeof(unsigned short);  // 335.5 MB

    unsigned short* xr = (unsigned short*)d_ws;
    unsigned short* h  = xr + XR_E;

    // 1) xr = hadamard(x) -> bf16
    {
        int ngroups = (int)(XR_E / 128);
        had_f32_to_bf16<<<dim3(ngroups / 4), dim3(256), 0, stream>>>(x, xr, ngroups);
    }

    if (ws_size >= need) {
        unsigned short* wgbf = h + H_E;
        unsigned short* wubf = wgbf + W_E;
        int total8 = (int)(W_E / 8);
        // 2) pre-dequant gate & up weights -> bf16
        dequant_w<<<dim3((total8 + 255) / 256), dim3(256), 0, stream>>>(wq_gate, s_gate, wgbf, D_DIM, total8);
        dequant_w<<<dim3((total8 + 255) / 256), dim3(256), 0, stream>>>(wq_up,   s_up,   wubf, D_DIM, total8);
        // 3) gate = xr @ Wg^T  (bf16, into h)
        gemm256<0><<<dim3((T_DIM / 256) * (I_DIM / 256)), dim3(512), 0, stream>>>(
            xr, wgbf, (void*)h, T_DIM, I_DIM, D_DIM);
        // 4) h = silu(gate) * (xr @ Wu^T)   (fused epilogue, in place over h)
        gemm256<1><<<dim3((T_DIM / 256) * (I_DIM / 256)), dim3(512), 0, stream>>>(
            xr, wubf, (void*)h, T_DIM, I_DIM, D_DIM);
        // 5) h = hadamard(h) in place
        {
            int ngroups = (int)(H_E / 128);
            had_bf16_inplace<<<dim3(ngroups / 4), dim3(256), 0, stream>>>(h, ngroups);
        }
        // 6) dequant down weights (reuse gate buffer)
        dequant_w<<<dim3((total8 + 255) / 256), dim3(256), 0, stream>>>(wq_down, s_down, wgbf, I_DIM, total8);
        // 7) out = h @ Wd^T  (f32)
        gemm256<2><<<dim3((T_DIM / 256) * (D_DIM / 256)), dim3(512), 0, stream>>>(
            h, wgbf, (void*)out, T_DIM, D_DIM, I_DIM);
    } else {
        // fallback: round-1 verified path (in-loop dequant)
        gemm_gateup_fb<<<dim3((T_DIM / 128) * (I_DIM / 128)), dim3(256), 0, stream>>>(
            xr, wq_gate, s_gate, wq_up, s_up, h);
        {
            int ngroups = (int)(H_E / 128);
            had_bf16_inplace<<<dim3(ngroups / 4), dim3(256), 0, stream>>>(h, ngroups);
        }
        gemm_down_fb<<<dim3((T_DIM / 128) * (D_DIM / 128)), dim3(256), 0, stream>>>(
            h, wq_down, s_down, out);
    }
}